// Round 16
// baseline (57.198 us; speedup 1.0000x reference)
//
#include <hip/hip_runtime.h>
#include <hip/hip_bf16.h>

#define SCALE_2LOG2E 2.8853900817779268f   // 2*log2(e): folded into projections
#define LOG2E 1.4426950408889634f

#define NB 8
#define TQ 32
#define TK 2048
#define DD 256

typedef unsigned short u16;
typedef u16 u16x8 __attribute__((ext_vector_type(8)));
typedef __bf16 bf16x8 __attribute__((ext_vector_type(8)));
typedef float f32x4 __attribute__((ext_vector_type(4)));

// bf16 round-to-nearest-even split helpers (bit math: no header-type aliasing)
__device__ __forceinline__ u16 f2bf_u(float x) {
  unsigned int xi = __builtin_bit_cast(unsigned int, x);
  unsigned int r = (xi + 0x7fffu + ((xi >> 16) & 1u)) >> 16;
  return (u16)r;
}
__device__ __forceinline__ float bf2f(u16 u) {
  return __builtin_bit_cast(float, (unsigned int)u << 16);
}

// ---------------------------------------------------------------------------
// K0: fp32 -> bf16 hi/lo planes for Wk, Wq (64 blocks x 256 thr x 8 elems).
// ---------------------------------------------------------------------------
__global__ __launch_bounds__(256) void convert_kernel(
    const float* __restrict__ Wk, const float* __restrict__ Wq,
    u16* __restrict__ wkh, u16* __restrict__ wkl,
    u16* __restrict__ wqh, u16* __restrict__ wql) {
  const int bx = blockIdx.x;
  const float* src; u16 *dh, *dl; int base;
  if (bx < 32) { src = Wk; dh = wkh; dl = wkl; base = 0; }
  else         { src = Wq; dh = wqh; dl = wql; base = 32; }
  const int chunk = (bx - base) * 256 + threadIdx.x;   // 8-element chunk
  const float4* s4 = (const float4*)(src + chunk * 8);
  float4 x0 = s4[0], x1 = s4[1];
  const float xs[8] = {x0.x, x0.y, x0.z, x0.w, x1.x, x1.y, x1.z, x1.w};
  u16x8 h, l;
#pragma unroll
  for (int i = 0; i < 8; ++i) {
    u16 hh = f2bf_u(xs[i]);
    h[i] = hh;
    l[i] = f2bf_u(xs[i] - bf2f(hh));
  }
  *(u16x8*)(dh + chunk * 8) = h;
  *(u16x8*)(dl + chunk * 8) = l;
}

// ---------------------------------------------------------------------------
// K1: fused convert+GEMM. C[m][u] = exp2(SCALE * sum_d A[m][d]*W[u][d]).
// Tile 64(m) x 256(n) (R13-validated; R14's 32-tile doubled B-staging work).
// 512 thr = 8 waves, wave = 32x64 output. BK=64, 4 ksteps.
// R15: register PREFETCH across the MFMA loop — issue ks+1 global loads right
// after the LDS-write barrier, so they fly during the MFMA phase. Pure code
// motion: barrier count unchanged (R12's failure added barriers; this doesn't).
// ---------------------------------------------------------------------------
__global__ __launch_bounds__(512) void proj_fused(
    const float* __restrict__ keys, const float* __restrict__ query,
    const u16* __restrict__ wkh, const u16* __restrict__ wkl,
    const u16* __restrict__ wqh, const u16* __restrict__ wql,
    float* __restrict__ ekpo, float* __restrict__ eqpo) {
  __shared__ u16 Ah[64 * 64], Al[64 * 64];
  __shared__ u16 Bh[256 * 64], Bl[256 * 64];
  const int tid = threadIdx.x, lane = tid & 63, wv = tid >> 6;
  const int bx = blockIdx.x;
  const float* A; const u16 *bhg, *blg; float* C; int m0;
  if (bx < 256) { A = keys;  bhg = wkh; blg = wkl; C = ekpo; m0 = bx * 64; }
  else          { A = query; bhg = wqh; blg = wql; C = eqpo; m0 = (bx - 256) * 64; }
  const int wr = (wv >> 2) * 32, wc = (wv & 3) * 64;

  const int arow = tid >> 3, ac = tid & 7;             // A: row 0..63, chunk 0..7
  const float* ag = A + (m0 + arow) * 256 + ac * 8;
  const int aoff = arow * 64 + ((ac ^ (arow & 7)) << 3);

  // B staging geometry (constant across ksteps)
  int brow[4], bc[4], boff[4];
#pragma unroll
  for (int j = 0; j < 4; ++j) {
    int idx = tid + j * 512;                            // 0..2047
    brow[j] = idx >> 3; bc[j] = idx & 7;
    boff[j] = brow[j] * 64 + ((bc[j] ^ (brow[j] & 7)) << 3);
  }

  f32x4 acc[2][4];
#pragma unroll
  for (int i = 0; i < 2; ++i)
#pragma unroll
    for (int j = 0; j < 4; ++j) acc[i][j] = {0.f, 0.f, 0.f, 0.f};

  // prologue: load kstep 0
  float4 a0 = *(const float4*)(ag);
  float4 a1 = *(const float4*)(ag + 4);
  u16x8 sbh[4], sbl[4];
#pragma unroll
  for (int j = 0; j < 4; ++j) {
    sbh[j] = *(const u16x8*)(bhg + brow[j] * 256 + bc[j] * 8);
    sbl[j] = *(const u16x8*)(blg + brow[j] * 256 + bc[j] * 8);
  }

  for (int ks = 0; ks < 4; ++ks) {
    // convert A regs for this kstep
    const float as[8] = {a0.x, a0.y, a0.z, a0.w, a1.x, a1.y, a1.z, a1.w};
    u16x8 hA, lA;
#pragma unroll
    for (int i = 0; i < 8; ++i) {
      u16 hh = f2bf_u(as[i]);
      hA[i] = hh;
      lA[i] = f2bf_u(as[i] - bf2f(hh));
    }
    if (ks) __syncthreads();                            // prev-step reads done
    *(u16x8*)&Ah[aoff] = hA;
    *(u16x8*)&Al[aoff] = lA;
#pragma unroll
    for (int j = 0; j < 4; ++j) {
      *(u16x8*)&Bh[boff[j]] = sbh[j];
      *(u16x8*)&Bl[boff[j]] = sbl[j];
    }
    __syncthreads();                                    // writes visible
    // prefetch next kstep: loads fly during the MFMA phase below
    if (ks < 3) {
      const int k1 = (ks + 1) * 64;
      a0 = *(const float4*)(ag + k1);
      a1 = *(const float4*)(ag + k1 + 4);
#pragma unroll
      for (int j = 0; j < 4; ++j) {
        sbh[j] = *(const u16x8*)(bhg + brow[j] * 256 + k1 + bc[j] * 8);
        sbl[j] = *(const u16x8*)(blg + brow[j] * 256 + k1 + bc[j] * 8);
      }
    }
#pragma unroll
    for (int s = 0; s < 2; ++s) {                       // ksub: 32 k each
      const int kc = s * 4 + (lane >> 4);               // 16B chunk in row
      bf16x8 fa[2][2], fb[4][2];                        // [frag][hi/lo]
#pragma unroll
      for (int mh = 0; mh < 2; ++mh) {
        int ra = wr + mh * 16 + (lane & 15);
        int off = ra * 64 + ((kc ^ (ra & 7)) << 3);
        fa[mh][0] = __builtin_bit_cast(bf16x8, *(const u16x8*)&Ah[off]);
        fa[mh][1] = __builtin_bit_cast(bf16x8, *(const u16x8*)&Al[off]);
      }
#pragma unroll
      for (int nh = 0; nh < 4; ++nh) {
        int rb = wc + nh * 16 + (lane & 15);
        int off = rb * 64 + ((kc ^ (rb & 7)) << 3);
        fb[nh][0] = __builtin_bit_cast(bf16x8, *(const u16x8*)&Bh[off]);
        fb[nh][1] = __builtin_bit_cast(bf16x8, *(const u16x8*)&Bl[off]);
      }
#pragma unroll
      for (int mh = 0; mh < 2; ++mh)
#pragma unroll
        for (int nh = 0; nh < 4; ++nh) {
          acc[mh][nh] = __builtin_amdgcn_mfma_f32_16x16x32_bf16(fa[mh][0], fb[nh][0], acc[mh][nh], 0, 0, 0);
          acc[mh][nh] = __builtin_amdgcn_mfma_f32_16x16x32_bf16(fa[mh][0], fb[nh][1], acc[mh][nh], 0, 0, 0);
          acc[mh][nh] = __builtin_amdgcn_mfma_f32_16x16x32_bf16(fa[mh][1], fb[nh][0], acc[mh][nh], 0, 0, 0);
        }
    }
  }
  // C/D layout (m89-verified): col = lane&15, row = (lane>>4)*4 + reg
#pragma unroll
  for (int mh = 0; mh < 2; ++mh)
#pragma unroll
    for (int nh = 0; nh < 4; ++nh)
#pragma unroll
      for (int j = 0; j < 4; ++j) {
        int row = m0 + wr + mh * 16 + (lane >> 4) * 4 + j;
        int col = wc + nh * 16 + (lane & 15);
        C[row * 256 + col] = __builtin_amdgcn_exp2f(acc[mh][nh][j] * SCALE_2LOG2E);
      }
}

// ---------------------------------------------------------------------------
// K2: fused score + PV, EK*EQ-factorized. R13 structure (validated best).
// grid (32 kc, 8 b, 2 qh) = 512 blocks (2/CU), 512 thr (8 waves, 2 q-rows ea).
// LDS 80KB: sbuf 64KB (ek swizzled) + eqlds 16KB (eq rows; K$-thrash fix).
// PV reads keys rows directly from global (coalesced 1KB/row, L2-resident).
// ---------------------------------------------------------------------------
__global__ __launch_bounds__(512) void score_ctx_kernel(
    const float* __restrict__ ekp, const float* __restrict__ eqp,
    const float* __restrict__ v, const float* __restrict__ keys,
    float* __restrict__ pbuf, float* __restrict__ part) {
  __shared__ float sbuf[64 * 256];     // 64 KB: ek chunk, XOR-swizzled
  __shared__ float eqlds[16 * 256];    // 16 KB: eq rows of this q-half
  const int tid = threadIdx.x;
  const int b = blockIdx.y;
  const int kc = blockIdx.x;
  const int qh = blockIdx.z;
  const int kbase = kc * 64;
#pragma unroll
  for (int i = 0; i < 8; ++i) {
    int idx4 = tid + i * 512;          // 0..4095 float4s
    int kk = idx4 >> 6, u4 = idx4 & 63;
    float4 t = *(const float4*)(ekp + (b * TK + kbase + kk) * 256 + u4 * 4);
    *(float4*)&sbuf[kk * 256 + ((u4 ^ (kk & 7)) << 2)] = t;
  }
#pragma unroll
  for (int i = 0; i < 2; ++i) {
    int idx4 = tid + i * 512;          // 0..1023 float4s: 16 rows x 64
    int r = idx4 >> 6, u4 = idx4 & 63;
    float4 t = *(const float4*)(eqp + (b * TQ + qh * 16 + r) * 256 + u4 * 4);
    *(float4*)&eqlds[r * 256 + u4 * 4] = t;
  }
  const int lane = tid & 63;
  float vs = (v[lane] + v[lane + 64]) + (v[lane + 128] + v[lane + 192]);
#pragma unroll
  for (int off = 32; off; off >>= 1) vs += __shfl_xor(vs, off, 64);
  __syncthreads();

  const int wv = tid >> 6;             // 0..7; q rows {qh*16+2wv, +1}
  const int q0 = qh * 16 + wv * 2;
  const int xorv = lane & 7;
  const float* eq0 = &eqlds[(wv * 2) * 256];   // uniform addr -> LDS broadcast
  const float* eq1 = eq0 + 256;
  float a00 = 0.f, a01 = 0.f, a10 = 0.f, a11 = 0.f;
#pragma unroll 4
  for (int u4 = 0; u4 < 64; ++u4) {
    float4 ekv = *(const float4*)&sbuf[lane * 256 + ((u4 ^ xorv) << 2)];
    float4 qa = *(const float4*)(eq0 + u4 * 4);   // LDS broadcast
    float4 qb = *(const float4*)(eq1 + u4 * 4);   // LDS broadcast
    float4 vv = *(const float4*)(v + u4 * 4);     // s_load, 1KB hot
    // row 0
    float A0 = fmaf(ekv.x, qa.x, 1.f);
    float A1 = fmaf(ekv.y, qa.y, 1.f);
    float A2 = fmaf(ekv.z, qa.z, 1.f);
    float A3 = fmaf(ekv.w, qa.w, 1.f);
    float n01 = fmaf(vv.x, A1, vv.y * A0);
    float n23 = fmaf(vv.z, A3, vv.w * A2);
    a00 = fmaf(n01, __builtin_amdgcn_rcpf(A0 * A1), a00);
    a01 = fmaf(n23, __builtin_amdgcn_rcpf(A2 * A3), a01);
    // row 1
    float B0 = fmaf(ekv.x, qb.x, 1.f);
    float B1 = fmaf(ekv.y, qb.y, 1.f);
    float B2 = fmaf(ekv.z, qb.z, 1.f);
    float B3 = fmaf(ekv.w, qb.w, 1.f);
    float m01 = fmaf(vv.x, B1, vv.y * B0);
    float m23 = fmaf(vv.z, B3, vv.w * B2);
    a10 = fmaf(m01, __builtin_amdgcn_rcpf(B0 * B1), a10);
    a11 = fmaf(m23, __builtin_amdgcn_rcpf(B2 * B3), a11);
  }
  float sc0 = fmaf(-2.f, a00 + a01, vs);          // |sc| <= ~13
  float sc1 = fmaf(-2.f, a10 + a11, vs);
  float p0 = __builtin_amdgcn_exp2f(sc0 * LOG2E);
  float p1 = __builtin_amdgcn_exp2f(sc1 * LOG2E);
  const int row0 = b * TQ + q0;
  pbuf[row0 * TK + kbase + lane] = p0;
  pbuf[(row0 + 1) * TK + kbase + lane] = p1;

  // PV: o[2 rows][256 d] partial = sum_k p[k]*keys[k][d]; lane = d-float4.
  float4 o0 = {0.f, 0.f, 0.f, 0.f}, o1 = {0.f, 0.f, 0.f, 0.f};
  const int ip0 = __builtin_bit_cast(int, p0);
  const int ip1 = __builtin_bit_cast(int, p1);
  const float* krow = keys + (b * TK + kbase) * 256 + lane * 4;
#pragma unroll 8
  for (int k = 0; k < 64; ++k) {
    float4 kv = *(const float4*)(krow + k * 256);
    float pk0 = __builtin_bit_cast(float, __builtin_amdgcn_readlane(ip0, k));
    float pk1 = __builtin_bit_cast(float, __builtin_amdgcn_readlane(ip1, k));
    o0.x = fmaf(pk0, kv.x, o0.x); o0.y = fmaf(pk0, kv.y, o0.y);
    o0.z = fmaf(pk0, kv.z, o0.z); o0.w = fmaf(pk0, kv.w, o0.w);
    o1.x = fmaf(pk1, kv.x, o1.x); o1.y = fmaf(pk1, kv.y, o1.y);
    o1.z = fmaf(pk1, kv.z, o1.z); o1.w = fmaf(pk1, kv.w, o1.w);
  }
  float* prow = part + (b * 32 + kc) * 8192 + q0 * 256 + lane * 4;
  *(float4*)prow = o0;
  *(float4*)(prow + 256) = o1;
}

// ---------------------------------------------------------------------------
// K3: combine. One block per (b,q) row, 256 thr.
// L = sum_k p[row][k]; attn = p*invL; ctx[d] = invL * sum_kc part[b][kc][q][d].
// ---------------------------------------------------------------------------
__global__ __launch_bounds__(256) void combine_kernel(
    const float* __restrict__ part, const float* __restrict__ pbuf,
    float* __restrict__ ctx, float* __restrict__ attn) {
  const int row = blockIdx.x;          // b*32 + q
  const int b = row >> 5, q = row & 31;
  const int tid = threadIdx.x;
  const float4* p4 = (const float4*)(pbuf + row * TK);
  float4 x0 = p4[tid], x1 = p4[tid + 256];
  float s = ((x0.x + x0.y) + (x0.z + x0.w)) + ((x1.x + x1.y) + (x1.z + x1.w));
#pragma unroll
  for (int off = 32; off; off >>= 1) s += __shfl_xor(s, off, 64);
  __shared__ float reds[4];
  __shared__ float sInvL;
  const int lane = tid & 63, wv = tid >> 6;
  if (lane == 0) reds[wv] = s;
  __syncthreads();
  if (tid == 0) {
    float L = (reds[0] + reds[1]) + (reds[2] + reds[3]);
    sInvL = __builtin_amdgcn_rcpf(L);
  }
  __syncthreads();
  const float invL = sInvL;
  // attn: 8 elems/thread
  float4* a4 = (float4*)(attn + row * TK);
  a4[tid] = make_float4(x0.x * invL, x0.y * invL, x0.z * invL, x0.w * invL);
  a4[tid + 256] = make_float4(x1.x * invL, x1.y * invL, x1.z * invL, x1.w * invL);
  // context: thread = d
  const float* p = part + b * 32 * 8192 + q * 256 + tid;
  float c0 = 0.f, c1 = 0.f, c2 = 0.f, c3 = 0.f;
#pragma unroll
  for (int kc = 0; kc < 8; ++kc) {
    c0 += p[(kc * 4 + 0) * 8192];
    c1 += p[(kc * 4 + 1) * 8192];
    c2 += p[(kc * 4 + 2) * 8192];
    c3 += p[(kc * 4 + 3) * 8192];
  }
  ctx[row * 256 + tid] = ((c0 + c1) + (c2 + c3)) * invL;
}

extern "C" void kernel_launch(void* const* d_in, const int* in_sizes, int n_in,
                              void* d_out, int out_size, void* d_ws, size_t ws_size,
                              hipStream_t stream) {
  const float* query = (const float*)d_in[0];  // [8][32][256]
  const float* keys  = (const float*)d_in[1];  // [8][2048][256]
  const float* Wq    = (const float*)d_in[2];  // [256][256]
  const float* Wk    = (const float*)d_in[3];  // [256][256]
  const float* v     = (const float*)d_in[4];  // [256]

  float* out  = (float*)d_out;
  float* ctx  = out;           // 65536 floats: context [8][32][256]
  float* attn = out + 65536;   // 524288 floats: attn [8][32][2048]

  float* ws   = (float*)d_ws;
  float* ekp  = ws;                  // 4194304 f  (= exp2(kp'))
  float* eqp  = ws + 4194304;        // 65536 f    (= exp2(qp'))
  float* pbuf = ws + 4259840;        // 524288 f
  float* part = ws + 4784128;        // 2097152 f
  u16* u   = (u16*)(ws + 6881280);
  u16* wkh = u;                      // 65536 u16 each
  u16* wkl = wkh + 65536;
  u16* wqh = wkl + 65536;
  u16* wql = wqh + 65536;

  convert_kernel<<<64, 256, 0, stream>>>(Wk, Wq, wkh, wkl, wqh, wql);
  proj_fused<<<260, 512, 0, stream>>>(keys, query, wkh, wkl, wqh, wql, ekp, eqp);
  score_ctx_kernel<<<dim3(32, 8, 2), 512, 0, stream>>>(ekp, eqp, v, keys, pbuf, part);
  combine_kernel<<<256, 256, 0, stream>>>(part, pbuf, ctx, attn);
}

// Round 17
// 54.271 us; speedup vs baseline: 1.0539x; 1.0539x over previous
//
#include <hip/hip_runtime.h>
#include <hip/hip_bf16.h>

#define SCALE_2LOG2E 2.8853900817779268f   // 2*log2(e): folded into projections
#define LOG2E 1.4426950408889634f

#define NB 8
#define TQ 32
#define TK 2048
#define DD 256

typedef unsigned short u16;
typedef u16 u16x8 __attribute__((ext_vector_type(8)));
typedef __bf16 bf16x8 __attribute__((ext_vector_type(8)));
typedef float f32x4 __attribute__((ext_vector_type(4)));

// bf16 round-to-nearest-even split helpers (bit math: no header-type aliasing)
__device__ __forceinline__ u16 f2bf_u(float x) {
  unsigned int xi = __builtin_bit_cast(unsigned int, x);
  unsigned int r = (xi + 0x7fffu + ((xi >> 16) & 1u)) >> 16;
  return (u16)r;
}
__device__ __forceinline__ float bf2f(u16 u) {
  return __builtin_bit_cast(float, (unsigned int)u << 16);
}

// ---------------------------------------------------------------------------
// K0: fp32 -> bf16 hi/lo planes for Wk, Wq (64 blocks x 256 thr x 8 elems).
// ---------------------------------------------------------------------------
__global__ __launch_bounds__(256) void convert_kernel(
    const float* __restrict__ Wk, const float* __restrict__ Wq,
    u16* __restrict__ wkh, u16* __restrict__ wkl,
    u16* __restrict__ wqh, u16* __restrict__ wql) {
  const int bx = blockIdx.x;
  const float* src; u16 *dh, *dl; int base;
  if (bx < 32) { src = Wk; dh = wkh; dl = wkl; base = 0; }
  else         { src = Wq; dh = wqh; dl = wql; base = 32; }
  const int chunk = (bx - base) * 256 + threadIdx.x;   // 8-element chunk
  const float4* s4 = (const float4*)(src + chunk * 8);
  float4 x0 = s4[0], x1 = s4[1];
  const float xs[8] = {x0.x, x0.y, x0.z, x0.w, x1.x, x1.y, x1.z, x1.w};
  u16x8 h, l;
#pragma unroll
  for (int i = 0; i < 8; ++i) {
    u16 hh = f2bf_u(xs[i]);
    h[i] = hh;
    l[i] = f2bf_u(xs[i] - bf2f(hh));
  }
  *(u16x8*)(dh + chunk * 8) = h;
  *(u16x8*)(dl + chunk * 8) = l;
}

// ---------------------------------------------------------------------------
// K1: fused convert+GEMM. C[m][u] = exp2(SCALE * sum_d A[m][d]*W[u][d]).
// Tile 64(m) x 256(n). 512 thr = 8 waves, wave = 32x64 output. BK=64.
// (R13-validated form: loads issued at loop head, no cross-MFMA prefetch —
// R15's prefetch variant regressed via register pressure at 1 block/CU.)
// ---------------------------------------------------------------------------
__global__ __launch_bounds__(512) void proj_fused(
    const float* __restrict__ keys, const float* __restrict__ query,
    const u16* __restrict__ wkh, const u16* __restrict__ wkl,
    const u16* __restrict__ wqh, const u16* __restrict__ wql,
    float* __restrict__ ekpo, float* __restrict__ eqpo) {
  __shared__ u16 Ah[64 * 64], Al[64 * 64];
  __shared__ u16 Bh[256 * 64], Bl[256 * 64];
  const int tid = threadIdx.x, lane = tid & 63, wv = tid >> 6;
  const int bx = blockIdx.x;
  const float* A; const u16 *bhg, *blg; float* C; int m0;
  if (bx < 256) { A = keys;  bhg = wkh; blg = wkl; C = ekpo; m0 = bx * 64; }
  else          { A = query; bhg = wqh; blg = wql; C = eqpo; m0 = (bx - 256) * 64; }
  const int wr = (wv >> 2) * 32, wc = (wv & 3) * 64;

  const int arow = tid >> 3, ac = tid & 7;             // A: row 0..63, chunk 0..7
  const float* ag = A + (m0 + arow) * 256 + ac * 8;
  const int aoff = arow * 64 + ((ac ^ (arow & 7)) << 3);

  f32x4 acc[2][4];
#pragma unroll
  for (int i = 0; i < 2; ++i)
#pragma unroll
    for (int j = 0; j < 4; ++j) acc[i][j] = {0.f, 0.f, 0.f, 0.f};

  for (int ks = 0; ks < 4; ++ks) {
    const int k0 = ks * 64;
    float4 a0 = *(const float4*)(ag + k0);
    float4 a1 = *(const float4*)(ag + k0 + 4);
    u16x8 sbh[4], sbl[4];
    int boff[4];
#pragma unroll
    for (int j = 0; j < 4; ++j) {
      int idx = tid + j * 512;                          // 0..2047
      int row = idx >> 3, c = idx & 7;
      sbh[j] = *(const u16x8*)(bhg + row * 256 + k0 + c * 8);
      sbl[j] = *(const u16x8*)(blg + row * 256 + k0 + c * 8);
      boff[j] = row * 64 + ((c ^ (row & 7)) << 3);
    }
    const float as[8] = {a0.x, a0.y, a0.z, a0.w, a1.x, a1.y, a1.z, a1.w};
    u16x8 hA, lA;
#pragma unroll
    for (int i = 0; i < 8; ++i) {
      u16 hh = f2bf_u(as[i]);
      hA[i] = hh;
      lA[i] = f2bf_u(as[i] - bf2f(hh));
    }
    if (ks) __syncthreads();                            // prev-step reads done
    *(u16x8*)&Ah[aoff] = hA;
    *(u16x8*)&Al[aoff] = lA;
#pragma unroll
    for (int j = 0; j < 4; ++j) {
      *(u16x8*)&Bh[boff[j]] = sbh[j];
      *(u16x8*)&Bl[boff[j]] = sbl[j];
    }
    __syncthreads();                                    // writes visible
#pragma unroll
    for (int s = 0; s < 2; ++s) {                       // ksub: 32 k each
      const int kc = s * 4 + (lane >> 4);               // 16B chunk in row
      bf16x8 fa[2][2], fb[4][2];                        // [frag][hi/lo]
#pragma unroll
      for (int mh = 0; mh < 2; ++mh) {
        int ra = wr + mh * 16 + (lane & 15);
        int off = ra * 64 + ((kc ^ (ra & 7)) << 3);
        fa[mh][0] = __builtin_bit_cast(bf16x8, *(const u16x8*)&Ah[off]);
        fa[mh][1] = __builtin_bit_cast(bf16x8, *(const u16x8*)&Al[off]);
      }
#pragma unroll
      for (int nh = 0; nh < 4; ++nh) {
        int rb = wc + nh * 16 + (lane & 15);
        int off = rb * 64 + ((kc ^ (rb & 7)) << 3);
        fb[nh][0] = __builtin_bit_cast(bf16x8, *(const u16x8*)&Bh[off]);
        fb[nh][1] = __builtin_bit_cast(bf16x8, *(const u16x8*)&Bl[off]);
      }
#pragma unroll
      for (int mh = 0; mh < 2; ++mh)
#pragma unroll
        for (int nh = 0; nh < 4; ++nh) {
          acc[mh][nh] = __builtin_amdgcn_mfma_f32_16x16x32_bf16(fa[mh][0], fb[nh][0], acc[mh][nh], 0, 0, 0);
          acc[mh][nh] = __builtin_amdgcn_mfma_f32_16x16x32_bf16(fa[mh][0], fb[nh][1], acc[mh][nh], 0, 0, 0);
          acc[mh][nh] = __builtin_amdgcn_mfma_f32_16x16x32_bf16(fa[mh][1], fb[nh][0], acc[mh][nh], 0, 0, 0);
        }
    }
  }
  // C/D layout (m89-verified): col = lane&15, row = (lane>>4)*4 + reg
#pragma unroll
  for (int mh = 0; mh < 2; ++mh)
#pragma unroll
    for (int nh = 0; nh < 4; ++nh)
#pragma unroll
      for (int j = 0; j < 4; ++j) {
        int row = m0 + wr + mh * 16 + (lane >> 4) * 4 + j;
        int col = wc + nh * 16 + (lane & 15);
        C[row * 256 + col] = __builtin_amdgcn_exp2f(acc[mh][nh][j] * SCALE_2LOG2E);
      }
}

// ---------------------------------------------------------------------------
// K2: fused score + PV, EK*EQ-factorized. R13 structure (validated best).
// grid (32 kc, 8 b, 2 qh) = 512 blocks (2/CU), 512 thr (8 waves, 2 q-rows ea).
// LDS 80KB: sbuf 64KB (ek swizzled) + eqlds 16KB (eq rows; K$-thrash fix).
// PV reads keys rows directly from global (coalesced 1KB/row, L2-resident).
// ---------------------------------------------------------------------------
__global__ __launch_bounds__(512) void score_ctx_kernel(
    const float* __restrict__ ekp, const float* __restrict__ eqp,
    const float* __restrict__ v, const float* __restrict__ keys,
    float* __restrict__ pbuf, float* __restrict__ part) {
  __shared__ float sbuf[64 * 256];     // 64 KB: ek chunk, XOR-swizzled
  __shared__ float eqlds[16 * 256];    // 16 KB: eq rows of this q-half
  const int tid = threadIdx.x;
  const int b = blockIdx.y;
  const int kc = blockIdx.x;
  const int qh = blockIdx.z;
  const int kbase = kc * 64;
#pragma unroll
  for (int i = 0; i < 8; ++i) {
    int idx4 = tid + i * 512;          // 0..4095 float4s
    int kk = idx4 >> 6, u4 = idx4 & 63;
    float4 t = *(const float4*)(ekp + (b * TK + kbase + kk) * 256 + u4 * 4);
    *(float4*)&sbuf[kk * 256 + ((u4 ^ (kk & 7)) << 2)] = t;
  }
#pragma unroll
  for (int i = 0; i < 2; ++i) {
    int idx4 = tid + i * 512;          // 0..1023 float4s: 16 rows x 64
    int r = idx4 >> 6, u4 = idx4 & 63;
    float4 t = *(const float4*)(eqp + (b * TQ + qh * 16 + r) * 256 + u4 * 4);
    *(float4*)&eqlds[r * 256 + u4 * 4] = t;
  }
  const int lane = tid & 63;
  float vs = (v[lane] + v[lane + 64]) + (v[lane + 128] + v[lane + 192]);
#pragma unroll
  for (int off = 32; off; off >>= 1) vs += __shfl_xor(vs, off, 64);
  __syncthreads();

  const int wv = tid >> 6;             // 0..7; q rows {qh*16+2wv, +1}
  const int q0 = qh * 16 + wv * 2;
  const int xorv = lane & 7;
  const float* eq0 = &eqlds[(wv * 2) * 256];   // uniform addr -> LDS broadcast
  const float* eq1 = eq0 + 256;
  float a00 = 0.f, a01 = 0.f, a10 = 0.f, a11 = 0.f;
#pragma unroll 4
  for (int u4 = 0; u4 < 64; ++u4) {
    float4 ekv = *(const float4*)&sbuf[lane * 256 + ((u4 ^ xorv) << 2)];
    float4 qa = *(const float4*)(eq0 + u4 * 4);   // LDS broadcast
    float4 qb = *(const float4*)(eq1 + u4 * 4);   // LDS broadcast
    float4 vv = *(const float4*)(v + u4 * 4);     // s_load, 1KB hot
    // row 0
    float A0 = fmaf(ekv.x, qa.x, 1.f);
    float A1 = fmaf(ekv.y, qa.y, 1.f);
    float A2 = fmaf(ekv.z, qa.z, 1.f);
    float A3 = fmaf(ekv.w, qa.w, 1.f);
    float n01 = fmaf(vv.x, A1, vv.y * A0);
    float n23 = fmaf(vv.z, A3, vv.w * A2);
    a00 = fmaf(n01, __builtin_amdgcn_rcpf(A0 * A1), a00);
    a01 = fmaf(n23, __builtin_amdgcn_rcpf(A2 * A3), a01);
    // row 1
    float B0 = fmaf(ekv.x, qb.x, 1.f);
    float B1 = fmaf(ekv.y, qb.y, 1.f);
    float B2 = fmaf(ekv.z, qb.z, 1.f);
    float B3 = fmaf(ekv.w, qb.w, 1.f);
    float m01 = fmaf(vv.x, B1, vv.y * B0);
    float m23 = fmaf(vv.z, B3, vv.w * B2);
    a10 = fmaf(m01, __builtin_amdgcn_rcpf(B0 * B1), a10);
    a11 = fmaf(m23, __builtin_amdgcn_rcpf(B2 * B3), a11);
  }
  float sc0 = fmaf(-2.f, a00 + a01, vs);          // |sc| <= ~13
  float sc1 = fmaf(-2.f, a10 + a11, vs);
  float p0 = __builtin_amdgcn_exp2f(sc0 * LOG2E);
  float p1 = __builtin_amdgcn_exp2f(sc1 * LOG2E);
  const int row0 = b * TQ + q0;
  pbuf[row0 * TK + kbase + lane] = p0;
  pbuf[(row0 + 1) * TK + kbase + lane] = p1;

  // PV: o[2 rows][256 d] partial = sum_k p[k]*keys[k][d]; lane = d-float4.
  float4 o0 = {0.f, 0.f, 0.f, 0.f}, o1 = {0.f, 0.f, 0.f, 0.f};
  const int ip0 = __builtin_bit_cast(int, p0);
  const int ip1 = __builtin_bit_cast(int, p1);
  const float* krow = keys + (b * TK + kbase) * 256 + lane * 4;
#pragma unroll 8
  for (int k = 0; k < 64; ++k) {
    float4 kv = *(const float4*)(krow + k * 256);
    float pk0 = __builtin_bit_cast(float, __builtin_amdgcn_readlane(ip0, k));
    float pk1 = __builtin_bit_cast(float, __builtin_amdgcn_readlane(ip1, k));
    o0.x = fmaf(pk0, kv.x, o0.x); o0.y = fmaf(pk0, kv.y, o0.y);
    o0.z = fmaf(pk0, kv.z, o0.z); o0.w = fmaf(pk0, kv.w, o0.w);
    o1.x = fmaf(pk1, kv.x, o1.x); o1.y = fmaf(pk1, kv.y, o1.y);
    o1.z = fmaf(pk1, kv.z, o1.z); o1.w = fmaf(pk1, kv.w, o1.w);
  }
  float* prow = part + (b * 32 + kc) * 8192 + q0 * 256 + lane * 4;
  *(float4*)prow = o0;
  *(float4*)(prow + 256) = o1;
}

// ---------------------------------------------------------------------------
// K3: combine. One block per (b,q) row, 256 thr.
// L = sum_k p[row][k]; attn = p*invL; ctx[d] = invL * sum_kc part[b][kc][q][d].
// ---------------------------------------------------------------------------
__global__ __launch_bounds__(256) void combine_kernel(
    const float* __restrict__ part, const float* __restrict__ pbuf,
    float* __restrict__ ctx, float* __restrict__ attn) {
  const int row = blockIdx.x;          // b*32 + q
  const int b = row >> 5, q = row & 31;
  const int tid = threadIdx.x;
  const float4* p4 = (const float4*)(pbuf + row * TK);
  float4 x0 = p4[tid], x1 = p4[tid + 256];
  float s = ((x0.x + x0.y) + (x0.z + x0.w)) + ((x1.x + x1.y) + (x1.z + x1.w));
#pragma unroll
  for (int off = 32; off; off >>= 1) s += __shfl_xor(s, off, 64);
  __shared__ float reds[4];
  __shared__ float sInvL;
  const int lane = tid & 63, wv = tid >> 6;
  if (lane == 0) reds[wv] = s;
  __syncthreads();
  if (tid == 0) {
    float L = (reds[0] + reds[1]) + (reds[2] + reds[3]);
    sInvL = __builtin_amdgcn_rcpf(L);
  }
  __syncthreads();
  const float invL = sInvL;
  // attn: 8 elems/thread
  float4* a4 = (float4*)(attn + row * TK);
  a4[tid] = make_float4(x0.x * invL, x0.y * invL, x0.z * invL, x0.w * invL);
  a4[tid + 256] = make_float4(x1.x * invL, x1.y * invL, x1.z * invL, x1.w * invL);
  // context: thread = d
  const float* p = part + b * 32 * 8192 + q * 256 + tid;
  float c0 = 0.f, c1 = 0.f, c2 = 0.f, c3 = 0.f;
#pragma unroll
  for (int kc = 0; kc < 8; ++kc) {
    c0 += p[(kc * 4 + 0) * 8192];
    c1 += p[(kc * 4 + 1) * 8192];
    c2 += p[(kc * 4 + 2) * 8192];
    c3 += p[(kc * 4 + 3) * 8192];
  }
  ctx[row * 256 + tid] = ((c0 + c1) + (c2 + c3)) * invL;
}

extern "C" void kernel_launch(void* const* d_in, const int* in_sizes, int n_in,
                              void* d_out, int out_size, void* d_ws, size_t ws_size,
                              hipStream_t stream) {
  const float* query = (const float*)d_in[0];  // [8][32][256]
  const float* keys  = (const float*)d_in[1];  // [8][2048][256]
  const float* Wq    = (const float*)d_in[2];  // [256][256]
  const float* Wk    = (const float*)d_in[3];  // [256][256]
  const float* v     = (const float*)d_in[4];  // [256]

  float* out  = (float*)d_out;
  float* ctx  = out;           // 65536 floats: context [8][32][256]
  float* attn = out + 65536;   // 524288 floats: attn [8][32][2048]

  float* ws   = (float*)d_ws;
  float* ekp  = ws;                  // 4194304 f  (= exp2(kp'))
  float* eqp  = ws + 4194304;        // 65536 f    (= exp2(qp'))
  float* pbuf = ws + 4259840;        // 524288 f
  float* part = ws + 4784128;        // 2097152 f
  u16* u   = (u16*)(ws + 6881280);
  u16* wkh = u;                      // 65536 u16 each
  u16* wkl = wkh + 65536;
  u16* wqh = wkl + 65536;
  u16* wql = wqh + 65536;

  convert_kernel<<<64, 256, 0, stream>>>(Wk, Wq, wkh, wkl, wqh, wql);
  proj_fused<<<260, 512, 0, stream>>>(keys, query, wkh, wkl, wqh, wql, ekp, eqp);
  score_ctx_kernel<<<dim3(32, 8, 2), 512, 0, stream>>>(ekp, eqp, v, keys, pbuf, part);
  combine_kernel<<<256, 256, 0, stream>>>(part, pbuf, ctx, attn);
}

// Round 18
// 53.913 us; speedup vs baseline: 1.0609x; 1.0067x over previous
//
#include <hip/hip_runtime.h>
#include <hip/hip_bf16.h>

#define SCALE_2LOG2E 2.8853900817779268f   // 2*log2(e): folded into projections
#define LOG2E 1.4426950408889634f

#define NB 8
#define TQ 32
#define TK 2048
#define DD 256

typedef unsigned short u16;
typedef u16 u16x8 __attribute__((ext_vector_type(8)));
typedef __bf16 bf16x8 __attribute__((ext_vector_type(8)));
typedef float f32x4 __attribute__((ext_vector_type(4)));

// bf16 round-to-nearest-even split helpers (bit math: no header-type aliasing)
__device__ __forceinline__ u16 f2bf_u(float x) {
  unsigned int xi = __builtin_bit_cast(unsigned int, x);
  unsigned int r = (xi + 0x7fffu + ((xi >> 16) & 1u)) >> 16;
  return (u16)r;
}
__device__ __forceinline__ float bf2f(u16 u) {
  return __builtin_bit_cast(float, (unsigned int)u << 16);
}

// ---------------------------------------------------------------------------
// K0: fp32 -> bf16 hi/lo planes for Wk, Wq (64 blocks x 256 thr x 8 elems).
// ---------------------------------------------------------------------------
__global__ __launch_bounds__(256) void convert_kernel(
    const float* __restrict__ Wk, const float* __restrict__ Wq,
    u16* __restrict__ wkh, u16* __restrict__ wkl,
    u16* __restrict__ wqh, u16* __restrict__ wql) {
  const int bx = blockIdx.x;
  const float* src; u16 *dh, *dl; int base;
  if (bx < 32) { src = Wk; dh = wkh; dl = wkl; base = 0; }
  else         { src = Wq; dh = wqh; dl = wql; base = 32; }
  const int chunk = (bx - base) * 256 + threadIdx.x;   // 8-element chunk
  const float4* s4 = (const float4*)(src + chunk * 8);
  float4 x0 = s4[0], x1 = s4[1];
  const float xs[8] = {x0.x, x0.y, x0.z, x0.w, x1.x, x1.y, x1.z, x1.w};
  u16x8 h, l;
#pragma unroll
  for (int i = 0; i < 8; ++i) {
    u16 hh = f2bf_u(xs[i]);
    h[i] = hh;
    l[i] = f2bf_u(xs[i] - bf2f(hh));
  }
  *(u16x8*)(dh + chunk * 8) = h;
  *(u16x8*)(dl + chunk * 8) = l;
}

// ---------------------------------------------------------------------------
// K1: fused convert+GEMM. C[m][u] = exp2(SCALE * sum_d A[m][d]*W[u][d]).
// Tile 64(m) x 256(n). 512 thr = 8 waves, wave = 32x64 output. BK=64.
// (R13-validated form.)
// ---------------------------------------------------------------------------
__global__ __launch_bounds__(512) void proj_fused(
    const float* __restrict__ keys, const float* __restrict__ query,
    const u16* __restrict__ wkh, const u16* __restrict__ wkl,
    const u16* __restrict__ wqh, const u16* __restrict__ wql,
    float* __restrict__ ekpo, float* __restrict__ eqpo) {
  __shared__ u16 Ah[64 * 64], Al[64 * 64];
  __shared__ u16 Bh[256 * 64], Bl[256 * 64];
  const int tid = threadIdx.x, lane = tid & 63, wv = tid >> 6;
  const int bx = blockIdx.x;
  const float* A; const u16 *bhg, *blg; float* C; int m0;
  if (bx < 256) { A = keys;  bhg = wkh; blg = wkl; C = ekpo; m0 = bx * 64; }
  else          { A = query; bhg = wqh; blg = wql; C = eqpo; m0 = (bx - 256) * 64; }
  const int wr = (wv >> 2) * 32, wc = (wv & 3) * 64;

  const int arow = tid >> 3, ac = tid & 7;             // A: row 0..63, chunk 0..7
  const float* ag = A + (m0 + arow) * 256 + ac * 8;
  const int aoff = arow * 64 + ((ac ^ (arow & 7)) << 3);

  f32x4 acc[2][4];
#pragma unroll
  for (int i = 0; i < 2; ++i)
#pragma unroll
    for (int j = 0; j < 4; ++j) acc[i][j] = {0.f, 0.f, 0.f, 0.f};

  for (int ks = 0; ks < 4; ++ks) {
    const int k0 = ks * 64;
    float4 a0 = *(const float4*)(ag + k0);
    float4 a1 = *(const float4*)(ag + k0 + 4);
    u16x8 sbh[4], sbl[4];
    int boff[4];
#pragma unroll
    for (int j = 0; j < 4; ++j) {
      int idx = tid + j * 512;                          // 0..2047
      int row = idx >> 3, c = idx & 7;
      sbh[j] = *(const u16x8*)(bhg + row * 256 + k0 + c * 8);
      sbl[j] = *(const u16x8*)(blg + row * 256 + k0 + c * 8);
      boff[j] = row * 64 + ((c ^ (row & 7)) << 3);
    }
    const float as[8] = {a0.x, a0.y, a0.z, a0.w, a1.x, a1.y, a1.z, a1.w};
    u16x8 hA, lA;
#pragma unroll
    for (int i = 0; i < 8; ++i) {
      u16 hh = f2bf_u(as[i]);
      hA[i] = hh;
      lA[i] = f2bf_u(as[i] - bf2f(hh));
    }
    if (ks) __syncthreads();                            // prev-step reads done
    *(u16x8*)&Ah[aoff] = hA;
    *(u16x8*)&Al[aoff] = lA;
#pragma unroll
    for (int j = 0; j < 4; ++j) {
      *(u16x8*)&Bh[boff[j]] = sbh[j];
      *(u16x8*)&Bl[boff[j]] = sbl[j];
    }
    __syncthreads();                                    // writes visible
#pragma unroll
    for (int s = 0; s < 2; ++s) {                       // ksub: 32 k each
      const int kc = s * 4 + (lane >> 4);               // 16B chunk in row
      bf16x8 fa[2][2], fb[4][2];                        // [frag][hi/lo]
#pragma unroll
      for (int mh = 0; mh < 2; ++mh) {
        int ra = wr + mh * 16 + (lane & 15);
        int off = ra * 64 + ((kc ^ (ra & 7)) << 3);
        fa[mh][0] = __builtin_bit_cast(bf16x8, *(const u16x8*)&Ah[off]);
        fa[mh][1] = __builtin_bit_cast(bf16x8, *(const u16x8*)&Al[off]);
      }
#pragma unroll
      for (int nh = 0; nh < 4; ++nh) {
        int rb = wc + nh * 16 + (lane & 15);
        int off = rb * 64 + ((kc ^ (rb & 7)) << 3);
        fb[nh][0] = __builtin_bit_cast(bf16x8, *(const u16x8*)&Bh[off]);
        fb[nh][1] = __builtin_bit_cast(bf16x8, *(const u16x8*)&Bl[off]);
      }
#pragma unroll
      for (int mh = 0; mh < 2; ++mh)
#pragma unroll
        for (int nh = 0; nh < 4; ++nh) {
          acc[mh][nh] = __builtin_amdgcn_mfma_f32_16x16x32_bf16(fa[mh][0], fb[nh][0], acc[mh][nh], 0, 0, 0);
          acc[mh][nh] = __builtin_amdgcn_mfma_f32_16x16x32_bf16(fa[mh][0], fb[nh][1], acc[mh][nh], 0, 0, 0);
          acc[mh][nh] = __builtin_amdgcn_mfma_f32_16x16x32_bf16(fa[mh][1], fb[nh][0], acc[mh][nh], 0, 0, 0);
        }
    }
  }
  // C/D layout (m89-verified): col = lane&15, row = (lane>>4)*4 + reg
#pragma unroll
  for (int mh = 0; mh < 2; ++mh)
#pragma unroll
    for (int nh = 0; nh < 4; ++nh)
#pragma unroll
      for (int j = 0; j < 4; ++j) {
        int row = m0 + wr + mh * 16 + (lane >> 4) * 4 + j;
        int col = wc + nh * 16 + (lane & 15);
        C[row * 256 + col] = __builtin_amdgcn_exp2f(acc[mh][nh][j] * SCALE_2LOG2E);
      }
}

// ---------------------------------------------------------------------------
// K2: fused score + PV, EK*EQ-factorized. R13 structure + R17 QUAD-rcp:
// v0/A0+v1/A1+v2/A2+v3/A3 = (n01*A23 + n23*A01) * rcp(A01*A23)
// -> 2 rcp/iter instead of 4 (trans issue 32->16 cyc), +4 VALU.
// A in [1, ~2^25]; A01*A23 <= ~2^100 << fp32 max — no overflow/underflow.
// grid (32 kc, 8 b, 2 qh) = 512 blocks (2/CU), 512 thr (8 waves, 2 q-rows ea).
// LDS 80KB: sbuf 64KB (ek swizzled) + eqlds 16KB (eq rows; K$-thrash fix).
// PV reads keys rows directly from global (coalesced 1KB/row, L2-resident).
// ---------------------------------------------------------------------------
__global__ __launch_bounds__(512) void score_ctx_kernel(
    const float* __restrict__ ekp, const float* __restrict__ eqp,
    const float* __restrict__ v, const float* __restrict__ keys,
    float* __restrict__ pbuf, float* __restrict__ part) {
  __shared__ float sbuf[64 * 256];     // 64 KB: ek chunk, XOR-swizzled
  __shared__ float eqlds[16 * 256];    // 16 KB: eq rows of this q-half
  const int tid = threadIdx.x;
  const int b = blockIdx.y;
  const int kc = blockIdx.x;
  const int qh = blockIdx.z;
  const int kbase = kc * 64;
#pragma unroll
  for (int i = 0; i < 8; ++i) {
    int idx4 = tid + i * 512;          // 0..4095 float4s
    int kk = idx4 >> 6, u4 = idx4 & 63;
    float4 t = *(const float4*)(ekp + (b * TK + kbase + kk) * 256 + u4 * 4);
    *(float4*)&sbuf[kk * 256 + ((u4 ^ (kk & 7)) << 2)] = t;
  }
#pragma unroll
  for (int i = 0; i < 2; ++i) {
    int idx4 = tid + i * 512;          // 0..1023 float4s: 16 rows x 64
    int r = idx4 >> 6, u4 = idx4 & 63;
    float4 t = *(const float4*)(eqp + (b * TQ + qh * 16 + r) * 256 + u4 * 4);
    *(float4*)&eqlds[r * 256 + u4 * 4] = t;
  }
  const int lane = tid & 63;
  float vs = (v[lane] + v[lane + 64]) + (v[lane + 128] + v[lane + 192]);
#pragma unroll
  for (int off = 32; off; off >>= 1) vs += __shfl_xor(vs, off, 64);
  __syncthreads();

  const int wv = tid >> 6;             // 0..7; q rows {qh*16+2wv, +1}
  const int q0 = qh * 16 + wv * 2;
  const int xorv = lane & 7;
  const float* eq0 = &eqlds[(wv * 2) * 256];   // uniform addr -> LDS broadcast
  const float* eq1 = eq0 + 256;
  float a00 = 0.f, a01 = 0.f, a10 = 0.f, a11 = 0.f;
#pragma unroll 4
  for (int u4 = 0; u4 < 64; ++u4) {
    float4 ekv = *(const float4*)&sbuf[lane * 256 + ((u4 ^ xorv) << 2)];
    float4 qa = *(const float4*)(eq0 + u4 * 4);   // LDS broadcast
    float4 qb = *(const float4*)(eq1 + u4 * 4);   // LDS broadcast
    float4 vv = *(const float4*)(v + u4 * 4);     // s_load, 1KB hot
    // row 0: quad-rcp
    float A0 = fmaf(ekv.x, qa.x, 1.f);
    float A1 = fmaf(ekv.y, qa.y, 1.f);
    float A2 = fmaf(ekv.z, qa.z, 1.f);
    float A3 = fmaf(ekv.w, qa.w, 1.f);
    float n01 = fmaf(vv.x, A1, vv.y * A0);
    float n23 = fmaf(vv.z, A3, vv.w * A2);
    float A01 = A0 * A1, A23 = A2 * A3;
    float num = fmaf(n01, A23, n23 * A01);
    if (u4 & 1) a01 = fmaf(num, __builtin_amdgcn_rcpf(A01 * A23), a01);
    else        a00 = fmaf(num, __builtin_amdgcn_rcpf(A01 * A23), a00);
    // row 1: quad-rcp
    float B0 = fmaf(ekv.x, qb.x, 1.f);
    float B1 = fmaf(ekv.y, qb.y, 1.f);
    float B2 = fmaf(ekv.z, qb.z, 1.f);
    float B3 = fmaf(ekv.w, qb.w, 1.f);
    float m01 = fmaf(vv.x, B1, vv.y * B0);
    float m23 = fmaf(vv.z, B3, vv.w * B2);
    float B01 = B0 * B1, B23 = B2 * B3;
    float mum = fmaf(m01, B23, m23 * B01);
    if (u4 & 1) a11 = fmaf(mum, __builtin_amdgcn_rcpf(B01 * B23), a11);
    else        a10 = fmaf(mum, __builtin_amdgcn_rcpf(B01 * B23), a10);
  }
  float sc0 = fmaf(-2.f, a00 + a01, vs);          // |sc| <= ~13
  float sc1 = fmaf(-2.f, a10 + a11, vs);
  float p0 = __builtin_amdgcn_exp2f(sc0 * LOG2E);
  float p1 = __builtin_amdgcn_exp2f(sc1 * LOG2E);
  const int row0 = b * TQ + q0;
  pbuf[row0 * TK + kbase + lane] = p0;
  pbuf[(row0 + 1) * TK + kbase + lane] = p1;

  // PV: o[2 rows][256 d] partial = sum_k p[k]*keys[k][d]; lane = d-float4.
  float4 o0 = {0.f, 0.f, 0.f, 0.f}, o1 = {0.f, 0.f, 0.f, 0.f};
  const int ip0 = __builtin_bit_cast(int, p0);
  const int ip1 = __builtin_bit_cast(int, p1);
  const float* krow = keys + (b * TK + kbase) * 256 + lane * 4;
#pragma unroll 8
  for (int k = 0; k < 64; ++k) {
    float4 kv = *(const float4*)(krow + k * 256);
    float pk0 = __builtin_bit_cast(float, __builtin_amdgcn_readlane(ip0, k));
    float pk1 = __builtin_bit_cast(float, __builtin_amdgcn_readlane(ip1, k));
    o0.x = fmaf(pk0, kv.x, o0.x); o0.y = fmaf(pk0, kv.y, o0.y);
    o0.z = fmaf(pk0, kv.z, o0.z); o0.w = fmaf(pk0, kv.w, o0.w);
    o1.x = fmaf(pk1, kv.x, o1.x); o1.y = fmaf(pk1, kv.y, o1.y);
    o1.z = fmaf(pk1, kv.z, o1.z); o1.w = fmaf(pk1, kv.w, o1.w);
  }
  float* prow = part + (b * 32 + kc) * 8192 + q0 * 256 + lane * 4;
  *(float4*)prow = o0;
  *(float4*)(prow + 256) = o1;
}

// ---------------------------------------------------------------------------
// K3: combine. One block per (b,q) row, 256 thr.
// L = sum_k p[row][k]; attn = p*invL; ctx[d] = invL * sum_kc part[b][kc][q][d].
// ---------------------------------------------------------------------------
__global__ __launch_bounds__(256) void combine_kernel(
    const float* __restrict__ part, const float* __restrict__ pbuf,
    float* __restrict__ ctx, float* __restrict__ attn) {
  const int row = blockIdx.x;          // b*32 + q
  const int b = row >> 5, q = row & 31;
  const int tid = threadIdx.x;
  const float4* p4 = (const float4*)(pbuf + row * TK);
  float4 x0 = p4[tid], x1 = p4[tid + 256];
  float s = ((x0.x + x0.y) + (x0.z + x0.w)) + ((x1.x + x1.y) + (x1.z + x1.w));
#pragma unroll
  for (int off = 32; off; off >>= 1) s += __shfl_xor(s, off, 64);
  __shared__ float reds[4];
  __shared__ float sInvL;
  const int lane = tid & 63, wv = tid >> 6;
  if (lane == 0) reds[wv] = s;
  __syncthreads();
  if (tid == 0) {
    float L = (reds[0] + reds[1]) + (reds[2] + reds[3]);
    sInvL = __builtin_amdgcn_rcpf(L);
  }
  __syncthreads();
  const float invL = sInvL;
  // attn: 8 elems/thread
  float4* a4 = (float4*)(attn + row * TK);
  a4[tid] = make_float4(x0.x * invL, x0.y * invL, x0.z * invL, x0.w * invL);
  a4[tid + 256] = make_float4(x1.x * invL, x1.y * invL, x1.z * invL, x1.w * invL);
  // context: thread = d
  const float* p = part + b * 32 * 8192 + q * 256 + tid;
  float c0 = 0.f, c1 = 0.f, c2 = 0.f, c3 = 0.f;
#pragma unroll
  for (int kc = 0; kc < 8; ++kc) {
    c0 += p[(kc * 4 + 0) * 8192];
    c1 += p[(kc * 4 + 1) * 8192];
    c2 += p[(kc * 4 + 2) * 8192];
    c3 += p[(kc * 4 + 3) * 8192];
  }
  ctx[row * 256 + tid] = ((c0 + c1) + (c2 + c3)) * invL;
}

extern "C" void kernel_launch(void* const* d_in, const int* in_sizes, int n_in,
                              void* d_out, int out_size, void* d_ws, size_t ws_size,
                              hipStream_t stream) {
  const float* query = (const float*)d_in[0];  // [8][32][256]
  const float* keys  = (const float*)d_in[1];  // [8][2048][256]
  const float* Wq    = (const float*)d_in[2];  // [256][256]
  const float* Wk    = (const float*)d_in[3];  // [256][256]
  const float* v     = (const float*)d_in[4];  // [256]

  float* out  = (float*)d_out;
  float* ctx  = out;           // 65536 floats: context [8][32][256]
  float* attn = out + 65536;   // 524288 floats: attn [8][32][2048]

  float* ws   = (float*)d_ws;
  float* ekp  = ws;                  // 4194304 f  (= exp2(kp'))
  float* eqp  = ws + 4194304;        // 65536 f    (= exp2(qp'))
  float* pbuf = ws + 4259840;        // 524288 f
  float* part = ws + 4784128;        // 2097152 f
  u16* u   = (u16*)(ws + 6881280);
  u16* wkh = u;                      // 65536 u16 each
  u16* wkl = wkh + 65536;
  u16* wqh = wkl + 65536;
  u16* wql = wqh + 65536;

  convert_kernel<<<64, 256, 0, stream>>>(Wk, Wq, wkh, wkl, wqh, wql);
  proj_fused<<<260, 512, 0, stream>>>(keys, query, wkh, wkl, wqh, wql, ekp, eqp);
  score_ctx_kernel<<<dim3(32, 8, 2), 512, 0, stream>>>(ekp, eqp, v, keys, pbuf, part);
  combine_kernel<<<256, 256, 0, stream>>>(part, pbuf, ctx, attn);
}

// Round 19
// 53.493 us; speedup vs baseline: 1.0693x; 1.0078x over previous
//
#include <hip/hip_runtime.h>
#include <hip/hip_bf16.h>

#define SCALE_2LOG2E 2.8853900817779268f   // 2*log2(e): folded into projections
#define LOG2E 1.4426950408889634f

#define NB 8
#define TQ 32
#define TK 2048
#define DD 256

typedef unsigned short u16;
typedef u16 u16x8 __attribute__((ext_vector_type(8)));
typedef __bf16 bf16x8 __attribute__((ext_vector_type(8)));
typedef float f32x4 __attribute__((ext_vector_type(4)));

// bf16 round-to-nearest-even split helpers (bit math: no header-type aliasing)
__device__ __forceinline__ u16 f2bf_u(float x) {
  unsigned int xi = __builtin_bit_cast(unsigned int, x);
  unsigned int r = (xi + 0x7fffu + ((xi >> 16) & 1u)) >> 16;
  return (u16)r;
}
__device__ __forceinline__ float bf2f(u16 u) {
  return __builtin_bit_cast(float, (unsigned int)u << 16);
}

// ---------------------------------------------------------------------------
// K1: fused convert+GEMM. C[m][u] = exp2(SCALE * sum_d A[m][d]*W[u][d]).
// Tile 64(m) x 256(n). 512 thr = 8 waves, wave = 32x64 output. BK=64.
// R18: BOTH operands converted fp32->bf16 hi/lo in-register during staging
// (was: A only; W came from a separate convert_kernel — now deleted, saving
// one dispatch + gap). Same bytes & load count; +~160 VALU/thread/kstep.
// ---------------------------------------------------------------------------
__global__ __launch_bounds__(512) void proj_fused(
    const float* __restrict__ keys, const float* __restrict__ query,
    const float* __restrict__ Wk, const float* __restrict__ Wq,
    float* __restrict__ ekpo, float* __restrict__ eqpo) {
  __shared__ u16 Ah[64 * 64], Al[64 * 64];
  __shared__ u16 Bh[256 * 64], Bl[256 * 64];
  const int tid = threadIdx.x, lane = tid & 63, wv = tid >> 6;
  const int bx = blockIdx.x;
  const float* A; const float* Wg; float* C; int m0;
  if (bx < 256) { A = keys;  Wg = Wk; C = ekpo; m0 = bx * 64; }
  else          { A = query; Wg = Wq; C = eqpo; m0 = (bx - 256) * 64; }
  const int wr = (wv >> 2) * 32, wc = (wv & 3) * 64;

  const int arow = tid >> 3, ac = tid & 7;             // A: row 0..63, chunk 0..7
  const float* ag = A + (m0 + arow) * 256 + ac * 8;
  const int aoff = arow * 64 + ((ac ^ (arow & 7)) << 3);

  f32x4 acc[2][4];
#pragma unroll
  for (int i = 0; i < 2; ++i)
#pragma unroll
    for (int j = 0; j < 4; ++j) acc[i][j] = {0.f, 0.f, 0.f, 0.f};

  for (int ks = 0; ks < 4; ++ks) {
    const int k0 = ks * 64;
    float4 a0 = *(const float4*)(ag + k0);
    float4 a1 = *(const float4*)(ag + k0 + 4);
    float4 wb0[4], wb1[4];
    int boff[4];
#pragma unroll
    for (int j = 0; j < 4; ++j) {
      int idx = tid + j * 512;                          // 0..2047
      int row = idx >> 3, c = idx & 7;
      wb0[j] = *(const float4*)(Wg + row * 256 + k0 + c * 8);
      wb1[j] = *(const float4*)(Wg + row * 256 + k0 + c * 8 + 4);
      boff[j] = row * 64 + ((c ^ (row & 7)) << 3);
    }
    // convert A in-register
    const float as[8] = {a0.x, a0.y, a0.z, a0.w, a1.x, a1.y, a1.z, a1.w};
    u16x8 hA, lA;
#pragma unroll
    for (int i = 0; i < 8; ++i) {
      u16 hh = f2bf_u(as[i]);
      hA[i] = hh;
      lA[i] = f2bf_u(as[i] - bf2f(hh));
    }
    // convert B in-register
    u16x8 hB[4], lB[4];
#pragma unroll
    for (int j = 0; j < 4; ++j) {
      const float bs[8] = {wb0[j].x, wb0[j].y, wb0[j].z, wb0[j].w,
                           wb1[j].x, wb1[j].y, wb1[j].z, wb1[j].w};
#pragma unroll
      for (int i = 0; i < 8; ++i) {
        u16 hh = f2bf_u(bs[i]);
        hB[j][i] = hh;
        lB[j][i] = f2bf_u(bs[i] - bf2f(hh));
      }
    }
    if (ks) __syncthreads();                            // prev-step reads done
    *(u16x8*)&Ah[aoff] = hA;
    *(u16x8*)&Al[aoff] = lA;
#pragma unroll
    for (int j = 0; j < 4; ++j) {
      *(u16x8*)&Bh[boff[j]] = hB[j];
      *(u16x8*)&Bl[boff[j]] = lB[j];
    }
    __syncthreads();                                    // writes visible
#pragma unroll
    for (int s = 0; s < 2; ++s) {                       // ksub: 32 k each
      const int kc = s * 4 + (lane >> 4);               // 16B chunk in row
      bf16x8 fa[2][2], fb[4][2];                        // [frag][hi/lo]
#pragma unroll
      for (int mh = 0; mh < 2; ++mh) {
        int ra = wr + mh * 16 + (lane & 15);
        int off = ra * 64 + ((kc ^ (ra & 7)) << 3);
        fa[mh][0] = __builtin_bit_cast(bf16x8, *(const u16x8*)&Ah[off]);
        fa[mh][1] = __builtin_bit_cast(bf16x8, *(const u16x8*)&Al[off]);
      }
#pragma unroll
      for (int nh = 0; nh < 4; ++nh) {
        int rb = wc + nh * 16 + (lane & 15);
        int off = rb * 64 + ((kc ^ (rb & 7)) << 3);
        fb[nh][0] = __builtin_bit_cast(bf16x8, *(const u16x8*)&Bh[off]);
        fb[nh][1] = __builtin_bit_cast(bf16x8, *(const u16x8*)&Bl[off]);
      }
#pragma unroll
      for (int mh = 0; mh < 2; ++mh)
#pragma unroll
        for (int nh = 0; nh < 4; ++nh) {
          acc[mh][nh] = __builtin_amdgcn_mfma_f32_16x16x32_bf16(fa[mh][0], fb[nh][0], acc[mh][nh], 0, 0, 0);
          acc[mh][nh] = __builtin_amdgcn_mfma_f32_16x16x32_bf16(fa[mh][0], fb[nh][1], acc[mh][nh], 0, 0, 0);
          acc[mh][nh] = __builtin_amdgcn_mfma_f32_16x16x32_bf16(fa[mh][1], fb[nh][0], acc[mh][nh], 0, 0, 0);
        }
    }
  }
  // C/D layout (m89-verified): col = lane&15, row = (lane>>4)*4 + reg
#pragma unroll
  for (int mh = 0; mh < 2; ++mh)
#pragma unroll
    for (int nh = 0; nh < 4; ++nh)
#pragma unroll
      for (int j = 0; j < 4; ++j) {
        int row = m0 + wr + mh * 16 + (lane >> 4) * 4 + j;
        int col = wc + nh * 16 + (lane & 15);
        C[row * 256 + col] = __builtin_amdgcn_exp2f(acc[mh][nh][j] * SCALE_2LOG2E);
      }
}

// ---------------------------------------------------------------------------
// K2: fused score + PV, EK*EQ-factorized. R13 structure + R17 quad-rcp.
// grid (32 kc, 8 b, 2 qh) = 512 blocks (2/CU), 512 thr (8 waves, 2 q-rows ea).
// LDS 80KB: sbuf 64KB (ek swizzled) + eqlds 16KB (eq rows; K$-thrash fix).
// PV reads keys rows directly from global (coalesced 1KB/row, L2-resident).
// ---------------------------------------------------------------------------
__global__ __launch_bounds__(512) void score_ctx_kernel(
    const float* __restrict__ ekp, const float* __restrict__ eqp,
    const float* __restrict__ v, const float* __restrict__ keys,
    float* __restrict__ pbuf, float* __restrict__ part) {
  __shared__ float sbuf[64 * 256];     // 64 KB: ek chunk, XOR-swizzled
  __shared__ float eqlds[16 * 256];    // 16 KB: eq rows of this q-half
  const int tid = threadIdx.x;
  const int b = blockIdx.y;
  const int kc = blockIdx.x;
  const int qh = blockIdx.z;
  const int kbase = kc * 64;
#pragma unroll
  for (int i = 0; i < 8; ++i) {
    int idx4 = tid + i * 512;          // 0..4095 float4s
    int kk = idx4 >> 6, u4 = idx4 & 63;
    float4 t = *(const float4*)(ekp + (b * TK + kbase + kk) * 256 + u4 * 4);
    *(float4*)&sbuf[kk * 256 + ((u4 ^ (kk & 7)) << 2)] = t;
  }
#pragma unroll
  for (int i = 0; i < 2; ++i) {
    int idx4 = tid + i * 512;          // 0..1023 float4s: 16 rows x 64
    int r = idx4 >> 6, u4 = idx4 & 63;
    float4 t = *(const float4*)(eqp + (b * TQ + qh * 16 + r) * 256 + u4 * 4);
    *(float4*)&eqlds[r * 256 + u4 * 4] = t;
  }
  const int lane = tid & 63;
  float vs = (v[lane] + v[lane + 64]) + (v[lane + 128] + v[lane + 192]);
#pragma unroll
  for (int off = 32; off; off >>= 1) vs += __shfl_xor(vs, off, 64);
  __syncthreads();

  const int wv = tid >> 6;             // 0..7; q rows {qh*16+2wv, +1}
  const int q0 = qh * 16 + wv * 2;
  const int xorv = lane & 7;
  const float* eq0 = &eqlds[(wv * 2) * 256];   // uniform addr -> LDS broadcast
  const float* eq1 = eq0 + 256;
  float a00 = 0.f, a01 = 0.f, a10 = 0.f, a11 = 0.f;
#pragma unroll 4
  for (int u4 = 0; u4 < 64; ++u4) {
    float4 ekv = *(const float4*)&sbuf[lane * 256 + ((u4 ^ xorv) << 2)];
    float4 qa = *(const float4*)(eq0 + u4 * 4);   // LDS broadcast
    float4 qb = *(const float4*)(eq1 + u4 * 4);   // LDS broadcast
    float4 vv = *(const float4*)(v + u4 * 4);     // s_load, 1KB hot
    // row 0: quad-rcp
    float A0 = fmaf(ekv.x, qa.x, 1.f);
    float A1 = fmaf(ekv.y, qa.y, 1.f);
    float A2 = fmaf(ekv.z, qa.z, 1.f);
    float A3 = fmaf(ekv.w, qa.w, 1.f);
    float n01 = fmaf(vv.x, A1, vv.y * A0);
    float n23 = fmaf(vv.z, A3, vv.w * A2);
    float A01 = A0 * A1, A23 = A2 * A3;
    float num = fmaf(n01, A23, n23 * A01);
    if (u4 & 1) a01 = fmaf(num, __builtin_amdgcn_rcpf(A01 * A23), a01);
    else        a00 = fmaf(num, __builtin_amdgcn_rcpf(A01 * A23), a00);
    // row 1: quad-rcp
    float B0 = fmaf(ekv.x, qb.x, 1.f);
    float B1 = fmaf(ekv.y, qb.y, 1.f);
    float B2 = fmaf(ekv.z, qb.z, 1.f);
    float B3 = fmaf(ekv.w, qb.w, 1.f);
    float m01 = fmaf(vv.x, B1, vv.y * B0);
    float m23 = fmaf(vv.z, B3, vv.w * B2);
    float B01 = B0 * B1, B23 = B2 * B3;
    float mum = fmaf(m01, B23, m23 * B01);
    if (u4 & 1) a11 = fmaf(mum, __builtin_amdgcn_rcpf(B01 * B23), a11);
    else        a10 = fmaf(mum, __builtin_amdgcn_rcpf(B01 * B23), a10);
  }
  float sc0 = fmaf(-2.f, a00 + a01, vs);          // |sc| <= ~13
  float sc1 = fmaf(-2.f, a10 + a11, vs);
  float p0 = __builtin_amdgcn_exp2f(sc0 * LOG2E);
  float p1 = __builtin_amdgcn_exp2f(sc1 * LOG2E);
  const int row0 = b * TQ + q0;
  pbuf[row0 * TK + kbase + lane] = p0;
  pbuf[(row0 + 1) * TK + kbase + lane] = p1;

  // PV: o[2 rows][256 d] partial = sum_k p[k]*keys[k][d]; lane = d-float4.
  float4 o0 = {0.f, 0.f, 0.f, 0.f}, o1 = {0.f, 0.f, 0.f, 0.f};
  const int ip0 = __builtin_bit_cast(int, p0);
  const int ip1 = __builtin_bit_cast(int, p1);
  const float* krow = keys + (b * TK + kbase) * 256 + lane * 4;
#pragma unroll 8
  for (int k = 0; k < 64; ++k) {
    float4 kv = *(const float4*)(krow + k * 256);
    float pk0 = __builtin_bit_cast(float, __builtin_amdgcn_readlane(ip0, k));
    float pk1 = __builtin_bit_cast(float, __builtin_amdgcn_readlane(ip1, k));
    o0.x = fmaf(pk0, kv.x, o0.x); o0.y = fmaf(pk0, kv.y, o0.y);
    o0.z = fmaf(pk0, kv.z, o0.z); o0.w = fmaf(pk0, kv.w, o0.w);
    o1.x = fmaf(pk1, kv.x, o1.x); o1.y = fmaf(pk1, kv.y, o1.y);
    o1.z = fmaf(pk1, kv.z, o1.z); o1.w = fmaf(pk1, kv.w, o1.w);
  }
  float* prow = part + (b * 32 + kc) * 8192 + q0 * 256 + lane * 4;
  *(float4*)prow = o0;
  *(float4*)(prow + 256) = o1;
}

// ---------------------------------------------------------------------------
// K3: combine. One block per (b,q) row, 256 thr.
// L = sum_k p[row][k]; attn = p*invL; ctx[d] = invL * sum_kc part[b][kc][q][d].
// ---------------------------------------------------------------------------
__global__ __launch_bounds__(256) void combine_kernel(
    const float* __restrict__ part, const float* __restrict__ pbuf,
    float* __restrict__ ctx, float* __restrict__ attn) {
  const int row = blockIdx.x;          // b*32 + q
  const int b = row >> 5, q = row & 31;
  const int tid = threadIdx.x;
  const float4* p4 = (const float4*)(pbuf + row * TK);
  float4 x0 = p4[tid], x1 = p4[tid + 256];
  float s = ((x0.x + x0.y) + (x0.z + x0.w)) + ((x1.x + x1.y) + (x1.z + x1.w));
#pragma unroll
  for (int off = 32; off; off >>= 1) s += __shfl_xor(s, off, 64);
  __shared__ float reds[4];
  __shared__ float sInvL;
  const int lane = tid & 63, wv = tid >> 6;
  if (lane == 0) reds[wv] = s;
  __syncthreads();
  if (tid == 0) {
    float L = (reds[0] + reds[1]) + (reds[2] + reds[3]);
    sInvL = __builtin_amdgcn_rcpf(L);
  }
  __syncthreads();
  const float invL = sInvL;
  // attn: 8 elems/thread
  float4* a4 = (float4*)(attn + row * TK);
  a4[tid] = make_float4(x0.x * invL, x0.y * invL, x0.z * invL, x0.w * invL);
  a4[tid + 256] = make_float4(x1.x * invL, x1.y * invL, x1.z * invL, x1.w * invL);
  // context: thread = d
  const float* p = part + b * 32 * 8192 + q * 256 + tid;
  float c0 = 0.f, c1 = 0.f, c2 = 0.f, c3 = 0.f;
#pragma unroll
  for (int kc = 0; kc < 8; ++kc) {
    c0 += p[(kc * 4 + 0) * 8192];
    c1 += p[(kc * 4 + 1) * 8192];
    c2 += p[(kc * 4 + 2) * 8192];
    c3 += p[(kc * 4 + 3) * 8192];
  }
  ctx[row * 256 + tid] = ((c0 + c1) + (c2 + c3)) * invL;
}

extern "C" void kernel_launch(void* const* d_in, const int* in_sizes, int n_in,
                              void* d_out, int out_size, void* d_ws, size_t ws_size,
                              hipStream_t stream) {
  const float* query = (const float*)d_in[0];  // [8][32][256]
  const float* keys  = (const float*)d_in[1];  // [8][2048][256]
  const float* Wq    = (const float*)d_in[2];  // [256][256]
  const float* Wk    = (const float*)d_in[3];  // [256][256]
  const float* v     = (const float*)d_in[4];  // [256]

  float* out  = (float*)d_out;
  float* ctx  = out;           // 65536 floats: context [8][32][256]
  float* attn = out + 65536;   // 524288 floats: attn [8][32][2048]

  float* ws   = (float*)d_ws;
  float* ekp  = ws;                  // 4194304 f  (= exp2(kp'))
  float* eqp  = ws + 4194304;        // 65536 f    (= exp2(qp'))
  float* pbuf = ws + 4259840;        // 524288 f
  float* part = ws + 4784128;        // 2097152 f

  proj_fused<<<260, 512, 0, stream>>>(keys, query, Wk, Wq, ekp, eqp);
  score_ctx_kernel<<<dim3(32, 8, 2), 512, 0, stream>>>(ekp, eqp, v, keys, pbuf, part);
  combine_kernel<<<256, 256, 0, stream>>>(part, pbuf, ctx, attn);
}